// Round 7
// baseline (400.849 us; speedup 1.0000x reference)
//
#include <hip/hip_runtime.h>
#include <hip/hip_bf16.h>
#include <stdint.h>

typedef unsigned short bf16_t;
typedef __attribute__((ext_vector_type(4))) short s4v;
typedef __attribute__((ext_vector_type(8))) short short8;
typedef __attribute__((ext_vector_type(4))) float f32x4;

__device__ __forceinline__ bf16_t f2b(float f) {
    union { float f; uint32_t u; } v; v.f = f;
    uint32_t u = v.u;
    return (bf16_t)((u + 0x7FFFu + ((u >> 16) & 1u)) >> 16);
}

__device__ __forceinline__ float b2f(bf16_t b) {
    union { uint32_t u; float f; } v;
    v.u = ((uint32_t)b) << 16;
    return v.f;
}

__global__ __launch_bounds__(256) void cvt_f32_bf16(const float* __restrict__ in,
                                                    bf16_t* __restrict__ out, int n4) {
    int i = blockIdx.x * blockDim.x + threadIdx.x;
    if (i >= n4) return;
    float4 f = ((const float4*)in)[i];
    ushort4 o;
    o.x = f2b(f.x); o.y = f2b(f.y); o.z = f2b(f.z); o.w = f2b(f.w);
    ((ushort4*)out)[i] = o;
}

// three 512x512 weight matrices in one launch
__global__ __launch_bounds__(256) void cvt_w3(const float* __restrict__ a,
                                              const float* __restrict__ b,
                                              const float* __restrict__ c,
                                              bf16_t* __restrict__ out) {
    int i = blockIdx.x * blockDim.x + threadIdx.x;   // 0..196607
    const int which = i >> 16;
    const int idx   = i & 65535;
    const float* src = (which == 0) ? a : (which == 1) ? b : c;
    float4 f = ((const float4*)src)[idx];
    ushort4 o;
    o.x = f2b(f.x); o.y = f2b(f.y); o.z = f2b(f.z); o.w = f2b(f.w);
    ((ushort4*)out)[i] = o;
}

__device__ __forceinline__ void lds_dma16(const void* g, void* l) {
    __builtin_amdgcn_global_load_lds(
        (const __attribute__((address_space(1))) void*)g,
        (__attribute__((address_space(3))) void*)l, 16, 0, 0);
}

// BK=64 swizzle contract: LDS[row][ch] holds global chunk (ch ^ (row&7));
// reader wanting global chunk g of row r reads LDS[r][g ^ (r&7)].
// 2-phase loop contract (T3 minimum recipe):
//   prologue: STAGE(buf0, kt=0); barrier.
//   iter kt:  STAGE(buf[cur^1], kt+1); ds_read+MFMA from buf[cur];
//             __syncthreads(); cur ^= 1.   One barrier per K-step.

// ---------- projections: Q/K/V fused, flat grid (1536 blocks) ----------
__global__ __launch_bounds__(256)
void proj_all(const bf16_t* __restrict__ Xb, const bf16_t* __restrict__ Wb,
              const float* __restrict__ qb, const float* __restrict__ kb,
              const float* __restrict__ vb,
              bf16_t* __restrict__ Qb, bf16_t* __restrict__ Kb,
              bf16_t* __restrict__ Vt)
{
    __shared__ __align__(16) bf16_t lds[2][16384];   // 64 KB: 2 x (A 16KB | B 16KB)

    const int tid  = threadIdx.x;
    const int lane = tid & 63;
    const int w    = tid >> 6;
    const int wm   = w & 1, wn = w >> 1;
    const int ll   = lane & 15;
    const int quad = lane >> 4;

    // xcd x owns m-panels [16x..16x+15]; inner = 4n x 3z per panel.
    const int bid   = blockIdx.x;
    const int x     = bid & 7;
    const int g     = bid >> 3;        // 0..191
    const int mi    = x * 16 + g / 12; // 0..127
    const int inner = g % 12;
    const int m0 = mi * 128;
    const int n0 = (inner & 3) * 128;
    const int z  = inner >> 2;         // 0..2

    const bf16_t* A = Xb;
    const bf16_t* B = Wb + z * 262144;

    auto stage = [&](int kt, int b) {
#pragma unroll
        for (int c = 0; c < 4; ++c) {
            const int base = (c * 4 + w) * 64;
            const int slot = base + lane;
            const int row  = slot >> 3;
            const int kc   = ((slot & 7) ^ (row & 7)) << 3;
            lds_dma16(A + (size_t)(m0 + row) * 512 + kt * 64 + kc, (char*)&lds[b][0]    + base * 16);
            lds_dma16(B + (size_t)(n0 + row) * 512 + kt * 64 + kc, (char*)&lds[b][8192] + base * 16);
        }
    };

    f32x4 acc[4][4];
#pragma unroll
    for (int i = 0; i < 4; i++)
#pragma unroll
        for (int j = 0; j < 4; j++) acc[i][j] = (f32x4){0.f, 0.f, 0.f, 0.f};

    stage(0, 0);
    __syncthreads();
    int cur = 0;
    for (int kt = 0; kt < 8; ++kt) {
        if (kt < 7) stage(kt + 1, cur ^ 1);
        const bf16_t* lsA = &lds[cur][0];
        const bf16_t* lsB = &lds[cur][8192];
#pragma unroll
        for (int t = 0; t < 2; t++) {
            short8 af[4], bf[4];
#pragma unroll
            for (int i = 0; i < 4; i++) {
                const int ri = wm * 64 + i * 16 + ll;
                const int rj = wn * 64 + i * 16 + ll;
                af[i] = *(const short8*)(lsA + ri * 64 + (((t * 4 + quad) ^ (ll & 7)) << 3));
                bf[i] = *(const short8*)(lsB + rj * 64 + (((t * 4 + quad) ^ (ll & 7)) << 3));
            }
#pragma unroll
            for (int i = 0; i < 4; i++)
#pragma unroll
                for (int j = 0; j < 4; j++)
                    acc[i][j] = __builtin_amdgcn_mfma_f32_16x16x32_bf16(af[i], bf[j], acc[i][j], 0, 0, 0);
        }
        __syncthreads();
        cur ^= 1;
    }

    // ---- epilogue: bounce through LDS for coalesced 16B stores ----
    bf16_t* wbuf = &lds[0][0] + w * 4096;     // 64x64 bf16 per wave (32 KB in buf0)
    const float inv = 0.044194173824159216f;  // 1/sqrt(512)

    if (z != 2) {
        const float* bptr = (z == 0) ? qb : kb;
        const float scl   = (z == 0) ? inv : 1.0f;
#pragma unroll
        for (int j = 0; j < 4; j++) {
            const int colL = j * 16 + ll;
            const float bv = bptr[n0 + wn * 64 + colL];
#pragma unroll
            for (int i = 0; i < 4; i++) {
                f32x4 a = acc[i][j];
#pragma unroll
                for (int r = 0; r < 4; r++) {
                    const int rowL = i * 16 + quad * 4 + r;
                    wbuf[rowL * 64 + (colL ^ ((rowL & 7) << 3))] = f2b((a[r] + bv) * scl);
                }
            }
        }
        __syncthreads();
        bf16_t* dst = (z == 0) ? Qb : Kb;
        const int rowg0 = m0 + wm * 64;
        const int colg0 = n0 + wn * 64;
#pragma unroll
        for (int k = 0; k < 8; k++) {
            const int rowL = (lane >> 3) + k * 8;
            const int c0   = (lane & 7) * 8;
            short8 vv = *(const short8*)(wbuf + rowL * 64 + (c0 ^ ((rowL & 7) << 3)));
            *(short8*)(dst + (size_t)(rowg0 + rowL) * 512 + colg0 + c0) = vv;
        }
    } else {
        // V: store transposed Vt[b][d][s]; bounce col-major (d-major)
#pragma unroll
        for (int j = 0; j < 4; j++) {
            const int d = j * 16 + ll;
            const float bv = vb[n0 + wn * 64 + d];
#pragma unroll
            for (int i = 0; i < 4; i++) {
                f32x4 a = acc[i][j];
                s4v pk;
                pk[0] = (short)f2b(a[0] + bv);
                pk[1] = (short)f2b(a[1] + bv);
                pk[2] = (short)f2b(a[2] + bv);
                pk[3] = (short)f2b(a[3] + bv);
                const int sB = i * 16 + quad * 4;
                *(s4v*)(wbuf + d * 64 + (sB ^ ((d & 7) << 3))) = pk;
            }
        }
        __syncthreads();
        const int rowg0 = m0 + wm * 64;
        const int b  = rowg0 >> 12;
        const int s0 = rowg0 & 4095;
        const int d0 = n0 + wn * 64;
#pragma unroll
        for (int k = 0; k < 8; k++) {
            const int dL = (lane >> 3) + k * 8;
            const int c0 = (lane & 7) * 8;
            short8 vv = *(const short8*)(wbuf + dL * 64 + (c0 ^ ((dL & 7) << 3)));
            *(short8*)(Vt + ((size_t)b * 512 + d0 + dL) * 4096 + s0 + c0) = vv;
        }
    }
}

// ---------- scores: P = sigmoid(Q K^T + bias_bf16), 2-phase dbuf ----------
// grid.x = 4096 flat: batch fastest (bias tile shared), then 4m x 8n supertiles.
// bias pre-converted to bf16 (halves the dominant 268 MB L2-miss bias traffic).
__global__ __launch_bounds__(256)
void scores_sig(const bf16_t* __restrict__ Qb, const bf16_t* __restrict__ Kb,
                const bf16_t* __restrict__ biasб, bf16_t* __restrict__ P)
{
    const bf16_t* __restrict__ biasb = biasб;
    __shared__ __align__(16) bf16_t lds[2][16384];   // 64 KB

    const int tid  = threadIdx.x;
    const int lane = tid & 63;
    const int w    = tid >> 6;
    const int wm   = w & 1, wn = w >> 1;
    const int ll   = lane & 15;
    const int quad = lane >> 4;

    const int bx  = blockIdx.x;
    const int z   = bx & 3;
    const int t_  = bx >> 2;              // 0..1023
    const int sup = t_ >> 5;              // 32 supertiles (8 in m x 4 in n)
    const int win = t_ & 31;              // 32 tiles per supertile (4m x 8n)
    const int m0  = ((sup >> 2) * 4 + (win & 3)) * 128;
    const int n0  = ((sup & 3) * 8 + (win >> 2)) * 128;

    const bf16_t* A = Qb + (size_t)z * 2097152;
    const bf16_t* B = Kb + (size_t)z * 2097152;
    bf16_t* out = P + (size_t)z * 16777216;

    auto stage = [&](int kt, int b) {
#pragma unroll
        for (int c = 0; c < 4; ++c) {
            const int base = (c * 4 + w) * 64;
            const int slot = base + lane;
            const int row  = slot >> 3;
            const int kc   = ((slot & 7) ^ (row & 7)) << 3;
            lds_dma16(A + (size_t)(m0 + row) * 512 + kt * 64 + kc, (char*)&lds[b][0]    + base * 16);
            lds_dma16(B + (size_t)(n0 + row) * 512 + kt * 64 + kc, (char*)&lds[b][8192] + base * 16);
        }
    };

    f32x4 acc[4][4];
#pragma unroll
    for (int i = 0; i < 4; i++)
#pragma unroll
        for (int j = 0; j < 4; j++) acc[i][j] = (f32x4){0.f, 0.f, 0.f, 0.f};

    stage(0, 0);
    __syncthreads();
    int cur = 0;
    for (int kt = 0; kt < 8; ++kt) {
        if (kt < 7) stage(kt + 1, cur ^ 1);
        const bf16_t* lsA = &lds[cur][0];
        const bf16_t* lsB = &lds[cur][8192];
#pragma unroll
        for (int t = 0; t < 2; t++) {
            short8 af[4], bf[4];
#pragma unroll
            for (int i = 0; i < 4; i++) {
                const int ri = wm * 64 + i * 16 + ll;
                const int rj = wn * 64 + i * 16 + ll;
                af[i] = *(const short8*)(lsA + ri * 64 + (((t * 4 + quad) ^ (ll & 7)) << 3));
                bf[i] = *(const short8*)(lsB + rj * 64 + (((t * 4 + quad) ^ (ll & 7)) << 3));
            }
#pragma unroll
            for (int i = 0; i < 4; i++)
#pragma unroll
                for (int j = 0; j < 4; j++)
                    acc[i][j] = __builtin_amdgcn_mfma_f32_16x16x32_bf16(af[i], bf[j], acc[i][j], 0, 0, 0);
        }
        __syncthreads();
        cur ^= 1;
    }

    // sigmoid epilogue: bf16 bias (shared by 4 batch-siblings), truncated pack
#pragma unroll
    for (int i = 0; i < 4; i++) {
#pragma unroll
        for (int j = 0; j < 4; j++) {
            const int col  = n0 + wn * 64 + j * 16 + ll;
            const int rowb = m0 + wm * 64 + i * 16 + quad * 4;
            f32x4 a = acc[i][j];
#pragma unroll
            for (int r = 0; r < 4; r++) {
                const int row = rowb + r;
                const float v = a[r] + b2f(biasb[(size_t)row * 4096 + col]);
                const float p = __builtin_amdgcn_rcpf(1.f + __expf(-v));
                out[(size_t)row * 4096 + col] = (bf16_t)(__float_as_uint(p) >> 16);
            }
        }
    }
}

// ---------- PV: out = P * Vt^T, BM=32 BN=512 (full D), 512 thr, 2 blocks/CU ----------
// P read exactly ONCE (round-2 measured: FETCH 82 MB at BN=512).  Grid 512 =
// 2 blocks/CU (68 KB LDS) so the co-resident block covers the barrier drain
// (round-2's 165 us failure was grid=256 = 1 block/CU starvation).
__global__ __launch_bounds__(512)
void pv_gemm(const bf16_t* __restrict__ P, const bf16_t* __restrict__ Vt,
             float* __restrict__ outg)
{
    __shared__ __align__(16) bf16_t lsA[32 * 64];    // 4 KB
    __shared__ __align__(16) bf16_t lsB[512 * 64];   // 64 KB

    const int tid  = threadIdx.x;
    const int lane = tid & 63;
    const int w    = tid >> 6;     // 0..7, owns 64-col group
    const int ll   = lane & 15;
    const int quad = lane >> 4;

    const int m0 = blockIdx.x * 32;   // 128 m-tiles
    const int z  = blockIdx.y;        // consecutive blocks share z -> Vt L2 reuse

    const bf16_t* A = P + (size_t)z * 16777216;   // [4096][4096]
    const bf16_t* B = Vt + (size_t)z * 2097152;   // [512][4096]
    float* out = outg + (size_t)z * 2097152;

    f32x4 acc[2][4];
#pragma unroll
    for (int i = 0; i < 2; i++)
#pragma unroll
        for (int j = 0; j < 4; j++) acc[i][j] = (f32x4){0.f, 0.f, 0.f, 0.f};

    for (int k0 = 0; k0 < 4096; k0 += 64) {
        // A: 32x8 = 256 chunks, staged by waves 0-3
        if (tid < 256) {
            const int slot = tid;
            const int row  = slot >> 3;
            const int kc   = ((slot & 7) ^ (row & 7)) << 3;
            lds_dma16(A + (size_t)(m0 + row) * 4096 + k0 + kc, (char*)lsA + slot * 16);
        }
        // B: 512x8 = 4096 chunks, 8 rounds of 512
#pragma unroll
        for (int c = 0; c < 8; ++c) {
            const int slot = c * 512 + tid;
            const int row  = slot >> 3;
            const int kc   = ((slot & 7) ^ (row & 7)) << 3;
            lds_dma16(B + (size_t)row * 4096 + k0 + kc, (char*)lsB + slot * 16);
        }
        __syncthreads();

#pragma unroll
        for (int t = 0; t < 2; t++) {
            short8 af[2], bf[4];
#pragma unroll
            for (int i = 0; i < 2; i++) {
                const int ri = i * 16 + ll;
                af[i] = *(const short8*)(lsA + ri * 64 + (((t * 4 + quad) ^ (ll & 7)) << 3));
            }
#pragma unroll
            for (int j = 0; j < 4; j++) {
                const int rj = w * 64 + j * 16 + ll;
                bf[j] = *(const short8*)(lsB + rj * 64 + (((t * 4 + quad) ^ (ll & 7)) << 3));
            }
#pragma unroll
            for (int i = 0; i < 2; i++)
#pragma unroll
                for (int j = 0; j < 4; j++)
                    acc[i][j] = __builtin_amdgcn_mfma_f32_16x16x32_bf16(af[i], bf[j], acc[i][j], 0, 0, 0);
        }
        __syncthreads();
    }

#pragma unroll
    for (int i = 0; i < 2; i++) {
#pragma unroll
        for (int j = 0; j < 4; j++) {
            const int col  = w * 64 + j * 16 + ll;
            const int rowb = m0 + i * 16 + quad * 4;
            f32x4 a = acc[i][j];
#pragma unroll
            for (int r = 0; r < 4; r++)
                out[(size_t)(rowb + r) * 512 + col] = a[r];
        }
    }
}

extern "C" void kernel_launch(void* const* d_in, const int* in_sizes, int n_in,
                              void* d_out, int out_size, void* d_ws, size_t ws_size,
                              hipStream_t stream) {
    (void)in_sizes; (void)n_in; (void)out_size; (void)ws_size;
    const float* x    = (const float*)d_in[0];
    const float* bias = (const float*)d_in[1];
    const float* Wq_w = (const float*)d_in[2];
    const float* Wq_b = (const float*)d_in[3];
    const float* Wk_w = (const float*)d_in[4];
    const float* Wk_b = (const float*)d_in[5];
    const float* Wv_w = (const float*)d_in[6];
    const float* Wv_b = (const float*)d_in[7];
    float* out = (float*)d_out;

    // workspace layout (bf16 elements)
    bf16_t* Xb = (bf16_t*)d_ws;                    // 16384 x 512
    bf16_t* Wb = Xb + (size_t)16384 * 512;         // 3 x 512 x 512
    bf16_t* Qb = Wb + (size_t)3 * 512 * 512;       // 16384 x 512 (pre-scaled 1/sqrt(D))
    bf16_t* Kb = Qb + (size_t)16384 * 512;         // 16384 x 512
    bf16_t* Vt = Kb + (size_t)16384 * 512;         // 4 x 512 x 4096 (transposed V)
    bf16_t* P  = Vt + (size_t)16384 * 512;         // 4 x 4096 x 4096
    // bf16 bias scratch: d_out (33,554,432 B) == 4096*4096*2 B exactly; out is
    // dead until pv_gemm overwrites it at the end.
    bf16_t* Bb = (bf16_t*)d_out;

    cvt_f32_bf16<<<8192, 256, 0, stream>>>(x, Xb, 2097152);
    cvt_w3<<<768, 256, 0, stream>>>(Wq_w, Wk_w, Wv_w, Wb);
    cvt_f32_bf16<<<16384, 256, 0, stream>>>(bias, Bb, 4194304);

    // all three projections in one launch
    proj_all<<<1536, 256, 0, stream>>>(Xb, Wb, Wq_b, Wk_b, Wv_b, Qb, Kb, Vt);
    // scores + sigmoid (2-phase dbuf, bf16 bias)
    scores_sig<<<4096, 256, 0, stream>>>(Qb, Kb, Bb, P);
    // out = P * V, 32x512 tiles (P read once), 512 threads, 2 blocks/CU
    pv_gemm<<<dim3(128, 4), 512, 0, stream>>>(P, Vt, out);
}

// Round 8
// 391.474 us; speedup vs baseline: 1.0239x; 1.0239x over previous
//
#include <hip/hip_runtime.h>
#include <hip/hip_bf16.h>
#include <stdint.h>

typedef unsigned short bf16_t;
typedef __attribute__((ext_vector_type(4))) short s4v;
typedef __attribute__((ext_vector_type(8))) short short8;
typedef __attribute__((ext_vector_type(4))) float f32x4;

__device__ __forceinline__ bf16_t f2b(float f) {
    union { float f; uint32_t u; } v; v.f = f;
    uint32_t u = v.u;
    return (bf16_t)((u + 0x7FFFu + ((u >> 16) & 1u)) >> 16);
}

__device__ __forceinline__ float b2f(bf16_t b) {
    union { uint32_t u; float f; } v;
    v.u = ((uint32_t)b) << 16;
    return v.f;
}

__global__ __launch_bounds__(256) void cvt_f32_bf16(const float* __restrict__ in,
                                                    bf16_t* __restrict__ out, int n4) {
    int i = blockIdx.x * blockDim.x + threadIdx.x;
    if (i >= n4) return;
    float4 f = ((const float4*)in)[i];
    ushort4 o;
    o.x = f2b(f.x); o.y = f2b(f.y); o.z = f2b(f.z); o.w = f2b(f.w);
    ((ushort4*)out)[i] = o;
}

// three 512x512 weight matrices in one launch
__global__ __launch_bounds__(256) void cvt_w3(const float* __restrict__ a,
                                              const float* __restrict__ b,
                                              const float* __restrict__ c,
                                              bf16_t* __restrict__ out) {
    int i = blockIdx.x * blockDim.x + threadIdx.x;   // 0..196607
    const int which = i >> 16;
    const int idx   = i & 65535;
    const float* src = (which == 0) ? a : (which == 1) ? b : c;
    float4 f = ((const float4*)src)[idx];
    ushort4 o;
    o.x = f2b(f.x); o.y = f2b(f.y); o.z = f2b(f.z); o.w = f2b(f.w);
    ((ushort4*)out)[i] = o;
}

__device__ __forceinline__ void lds_dma16(const void* g, void* l) {
    __builtin_amdgcn_global_load_lds(
        (const __attribute__((address_space(1))) void*)g,
        (__attribute__((address_space(3))) void*)l, 16, 0, 0);
}

// BK=64 swizzle contract: LDS[row][ch] holds global chunk (ch ^ (row&7));
// reader wanting global chunk g of row r reads LDS[r][g ^ (r&7)].
// 2-phase loop contract (T3 minimum recipe):
//   prologue: STAGE(buf0, kt=0); barrier.
//   iter kt:  STAGE(buf[cur^1], kt+1); ds_read+MFMA from buf[cur];
//             __syncthreads(); cur ^= 1.   One barrier per K-step.

// ---------- projections: Q/K/V fused (blocks 0..1535) + bias f32->bf16
// conversion tail (blocks 1536..3583, grid-stride) overlapped under proj ----------
__global__ __launch_bounds__(256)
void proj_all(const bf16_t* __restrict__ Xb, const bf16_t* __restrict__ Wb,
              const float* __restrict__ qb, const float* __restrict__ kb,
              const float* __restrict__ vb,
              bf16_t* __restrict__ Qb, bf16_t* __restrict__ Kb,
              bf16_t* __restrict__ Vt,
              const float* __restrict__ biasf, bf16_t* __restrict__ biasb)
{
    __shared__ __align__(16) bf16_t lds[2][16384];   // 64 KB: 2 x (A 16KB | B 16KB)

    const int tid  = threadIdx.x;
    const int bid  = blockIdx.x;

    if (bid >= 1536) {
        // ---- bias conversion tail: 2048 blocks x 256 thr, 8 float4 each ----
        const int base = (bid - 1536) * 256 + tid;   // 0..524287
#pragma unroll
        for (int k = 0; k < 8; ++k) {
            const int i = base + k * 524288;          // covers 4194304 float4s
            float4 f = ((const float4*)biasf)[i];
            ushort4 o;
            o.x = f2b(f.x); o.y = f2b(f.y); o.z = f2b(f.z); o.w = f2b(f.w);
            ((ushort4*)biasb)[i] = o;
        }
        return;
    }

    const int lane = tid & 63;
    const int w    = tid >> 6;
    const int wm   = w & 1, wn = w >> 1;
    const int ll   = lane & 15;
    const int quad = lane >> 4;

    // xcd x owns m-panels [16x..16x+15]; inner = 4n x 3z per panel.
    const int x     = bid & 7;
    const int g     = bid >> 3;        // 0..191
    const int mi    = x * 16 + g / 12; // 0..127
    const int inner = g % 12;
    const int m0 = mi * 128;
    const int n0 = (inner & 3) * 128;
    const int z  = inner >> 2;         // 0..2

    const bf16_t* A = Xb;
    const bf16_t* B = Wb + z * 262144;

    auto stage = [&](int kt, int b) {
#pragma unroll
        for (int c = 0; c < 4; ++c) {
            const int base = (c * 4 + w) * 64;
            const int slot = base + lane;
            const int row  = slot >> 3;
            const int kc   = ((slot & 7) ^ (row & 7)) << 3;
            lds_dma16(A + (size_t)(m0 + row) * 512 + kt * 64 + kc, (char*)&lds[b][0]    + base * 16);
            lds_dma16(B + (size_t)(n0 + row) * 512 + kt * 64 + kc, (char*)&lds[b][8192] + base * 16);
        }
    };

    f32x4 acc[4][4];
#pragma unroll
    for (int i = 0; i < 4; i++)
#pragma unroll
        for (int j = 0; j < 4; j++) acc[i][j] = (f32x4){0.f, 0.f, 0.f, 0.f};

    stage(0, 0);
    __syncthreads();
    int cur = 0;
    for (int kt = 0; kt < 8; ++kt) {
        if (kt < 7) stage(kt + 1, cur ^ 1);
        const bf16_t* lsA = &lds[cur][0];
        const bf16_t* lsB = &lds[cur][8192];
#pragma unroll
        for (int t = 0; t < 2; t++) {
            short8 af[4], bf[4];
#pragma unroll
            for (int i = 0; i < 4; i++) {
                const int ri = wm * 64 + i * 16 + ll;
                const int rj = wn * 64 + i * 16 + ll;
                af[i] = *(const short8*)(lsA + ri * 64 + (((t * 4 + quad) ^ (ll & 7)) << 3));
                bf[i] = *(const short8*)(lsB + rj * 64 + (((t * 4 + quad) ^ (ll & 7)) << 3));
            }
#pragma unroll
            for (int i = 0; i < 4; i++)
#pragma unroll
                for (int j = 0; j < 4; j++)
                    acc[i][j] = __builtin_amdgcn_mfma_f32_16x16x32_bf16(af[i], bf[j], acc[i][j], 0, 0, 0);
        }
        __syncthreads();
        cur ^= 1;
    }

    // ---- epilogue: bounce through LDS for coalesced 16B stores ----
    bf16_t* wbuf = &lds[0][0] + w * 4096;     // 64x64 bf16 per wave (32 KB in buf0)
    const float inv = 0.044194173824159216f;  // 1/sqrt(512)

    if (z != 2) {
        const float* bptr = (z == 0) ? qb : kb;
        const float scl   = (z == 0) ? inv : 1.0f;
#pragma unroll
        for (int j = 0; j < 4; j++) {
            const int colL = j * 16 + ll;
            const float bv = bptr[n0 + wn * 64 + colL];
#pragma unroll
            for (int i = 0; i < 4; i++) {
                f32x4 a = acc[i][j];
#pragma unroll
                for (int r = 0; r < 4; r++) {
                    const int rowL = i * 16 + quad * 4 + r;
                    wbuf[rowL * 64 + (colL ^ ((rowL & 7) << 3))] = f2b((a[r] + bv) * scl);
                }
            }
        }
        __syncthreads();
        bf16_t* dst = (z == 0) ? Qb : Kb;
        const int rowg0 = m0 + wm * 64;
        const int colg0 = n0 + wn * 64;
#pragma unroll
        for (int k = 0; k < 8; k++) {
            const int rowL = (lane >> 3) + k * 8;
            const int c0   = (lane & 7) * 8;
            short8 vv = *(const short8*)(wbuf + rowL * 64 + (c0 ^ ((rowL & 7) << 3)));
            *(short8*)(dst + (size_t)(rowg0 + rowL) * 512 + colg0 + c0) = vv;
        }
    } else {
        // V: store transposed Vt[b][d][s]; bounce col-major (d-major)
#pragma unroll
        for (int j = 0; j < 4; j++) {
            const int d = j * 16 + ll;
            const float bv = vb[n0 + wn * 64 + d];
#pragma unroll
            for (int i = 0; i < 4; i++) {
                f32x4 a = acc[i][j];
                s4v pk;
                pk[0] = (short)f2b(a[0] + bv);
                pk[1] = (short)f2b(a[1] + bv);
                pk[2] = (short)f2b(a[2] + bv);
                pk[3] = (short)f2b(a[3] + bv);
                const int sB = i * 16 + quad * 4;
                *(s4v*)(wbuf + d * 64 + (sB ^ ((d & 7) << 3))) = pk;
            }
        }
        __syncthreads();
        const int rowg0 = m0 + wm * 64;
        const int b  = rowg0 >> 12;
        const int s0 = rowg0 & 4095;
        const int d0 = n0 + wn * 64;
#pragma unroll
        for (int k = 0; k < 8; k++) {
            const int dL = (lane >> 3) + k * 8;
            const int c0 = (lane & 7) * 8;
            short8 vv = *(const short8*)(wbuf + dL * 64 + (c0 ^ ((dL & 7) << 3)));
            *(short8*)(Vt + ((size_t)b * 512 + d0 + dL) * 4096 + s0 + c0) = vv;
        }
    }
}

// ---------- scores: P = sigmoid(Q K^T + bias_bf16), 2-phase dbuf ----------
// grid.x = 4096 flat: batch fastest (bias tile shared), then 4m x 8n supertiles.
// bias pre-converted to bf16 (halves the dominant bias L2-miss traffic).
__global__ __launch_bounds__(256)
void scores_sig(const bf16_t* __restrict__ Qb, const bf16_t* __restrict__ Kb,
                const bf16_t* __restrict__ biasb, bf16_t* __restrict__ P)
{
    __shared__ __align__(16) bf16_t lds[2][16384];   // 64 KB

    const int tid  = threadIdx.x;
    const int lane = tid & 63;
    const int w    = tid >> 6;
    const int wm   = w & 1, wn = w >> 1;
    const int ll   = lane & 15;
    const int quad = lane >> 4;

    const int bx  = blockIdx.x;
    const int z   = bx & 3;
    const int t_  = bx >> 2;              // 0..1023
    const int sup = t_ >> 5;              // 32 supertiles (8 in m x 4 in n)
    const int win = t_ & 31;              // 32 tiles per supertile (4m x 8n)
    const int m0  = ((sup >> 2) * 4 + (win & 3)) * 128;
    const int n0  = ((sup & 3) * 8 + (win >> 2)) * 128;

    const bf16_t* A = Qb + (size_t)z * 2097152;
    const bf16_t* B = Kb + (size_t)z * 2097152;
    bf16_t* out = P + (size_t)z * 16777216;

    auto stage = [&](int kt, int b) {
#pragma unroll
        for (int c = 0; c < 4; ++c) {
            const int base = (c * 4 + w) * 64;
            const int slot = base + lane;
            const int row  = slot >> 3;
            const int kc   = ((slot & 7) ^ (row & 7)) << 3;
            lds_dma16(A + (size_t)(m0 + row) * 512 + kt * 64 + kc, (char*)&lds[b][0]    + base * 16);
            lds_dma16(B + (size_t)(n0 + row) * 512 + kt * 64 + kc, (char*)&lds[b][8192] + base * 16);
        }
    };

    f32x4 acc[4][4];
#pragma unroll
    for (int i = 0; i < 4; i++)
#pragma unroll
        for (int j = 0; j < 4; j++) acc[i][j] = (f32x4){0.f, 0.f, 0.f, 0.f};

    stage(0, 0);
    __syncthreads();
    int cur = 0;
    for (int kt = 0; kt < 8; ++kt) {
        if (kt < 7) stage(kt + 1, cur ^ 1);
        const bf16_t* lsA = &lds[cur][0];
        const bf16_t* lsB = &lds[cur][8192];
#pragma unroll
        for (int t = 0; t < 2; t++) {
            short8 af[4], bf[4];
#pragma unroll
            for (int i = 0; i < 4; i++) {
                const int ri = wm * 64 + i * 16 + ll;
                const int rj = wn * 64 + i * 16 + ll;
                af[i] = *(const short8*)(lsA + ri * 64 + (((t * 4 + quad) ^ (ll & 7)) << 3));
                bf[i] = *(const short8*)(lsB + rj * 64 + (((t * 4 + quad) ^ (ll & 7)) << 3));
            }
#pragma unroll
            for (int i = 0; i < 4; i++)
#pragma unroll
                for (int j = 0; j < 4; j++)
                    acc[i][j] = __builtin_amdgcn_mfma_f32_16x16x32_bf16(af[i], bf[j], acc[i][j], 0, 0, 0);
        }
        __syncthreads();
        cur ^= 1;
    }

    // sigmoid epilogue: bf16 bias (shared by 4 batch-siblings), truncated pack
#pragma unroll
    for (int i = 0; i < 4; i++) {
#pragma unroll
        for (int j = 0; j < 4; j++) {
            const int col  = n0 + wn * 64 + j * 16 + ll;
            const int rowb = m0 + wm * 64 + i * 16 + quad * 4;
            f32x4 a = acc[i][j];
#pragma unroll
            for (int r = 0; r < 4; r++) {
                const int row = rowb + r;
                const float v = a[r] + b2f(biasb[(size_t)row * 4096 + col]);
                const float p = __builtin_amdgcn_rcpf(1.f + __expf(-v));
                out[(size_t)row * 4096 + col] = (bf16_t)(__float_as_uint(p) >> 16);
            }
        }
    }
}

// ---------- PV: out = P * Vt^T, 128x128 tile, BK=64, K=4096, 2-phase dbuf ----------
// (round-6 verified config)
__global__ __launch_bounds__(256)
void pv_gemm(const bf16_t* __restrict__ P, const bf16_t* __restrict__ Vt,
             float* __restrict__ outg)
{
    __shared__ __align__(16) bf16_t lds[2][16384];   // 64 KB

    const int tid  = threadIdx.x;
    const int lane = tid & 63;
    const int w    = tid >> 6;
    const int wm   = w & 1, wn = w >> 1;
    const int ll   = lane & 15;
    const int quad = lane >> 4;

    const int n0 = blockIdx.x * 128;   // 0..511 (d dimension)
    const int m0 = blockIdx.y * 128;   // 0..4095 (q dimension)
    const int z  = blockIdx.z;

    const bf16_t* A = P + (size_t)z * 16777216;   // [4096][4096]
    const bf16_t* B = Vt + (size_t)z * 2097152;   // [512][4096]
    float* out = outg + (size_t)z * 2097152;

    auto stage = [&](int kt, int b) {
#pragma unroll
        for (int c = 0; c < 4; ++c) {
            const int base = (c * 4 + w) * 64;
            const int slot = base + lane;
            const int row  = slot >> 3;
            const int kc   = ((slot & 7) ^ (row & 7)) << 3;
            lds_dma16(A + (size_t)(m0 + row) * 4096 + kt * 64 + kc, (char*)&lds[b][0]    + base * 16);
            lds_dma16(B + (size_t)(n0 + row) * 4096 + kt * 64 + kc, (char*)&lds[b][8192] + base * 16);
        }
    };

    f32x4 acc[4][4];
#pragma unroll
    for (int i = 0; i < 4; i++)
#pragma unroll
        for (int j = 0; j < 4; j++) acc[i][j] = (f32x4){0.f, 0.f, 0.f, 0.f};

    stage(0, 0);
    __syncthreads();
    int cur = 0;
    for (int kt = 0; kt < 64; ++kt) {
        if (kt < 63) stage(kt + 1, cur ^ 1);
        const bf16_t* lsA = &lds[cur][0];
        const bf16_t* lsB = &lds[cur][8192];
#pragma unroll
        for (int t = 0; t < 2; t++) {
            short8 af[4], bf[4];
#pragma unroll
            for (int i = 0; i < 4; i++) {
                const int ri = wm * 64 + i * 16 + ll;
                const int rj = wn * 64 + i * 16 + ll;
                af[i] = *(const short8*)(lsA + ri * 64 + (((t * 4 + quad) ^ (ll & 7)) << 3));
                bf[i] = *(const short8*)(lsB + rj * 64 + (((t * 4 + quad) ^ (ll & 7)) << 3));
            }
#pragma unroll
            for (int i = 0; i < 4; i++)
#pragma unroll
                for (int j = 0; j < 4; j++)
                    acc[i][j] = __builtin_amdgcn_mfma_f32_16x16x32_bf16(af[i], bf[j], acc[i][j], 0, 0, 0);
        }
        __syncthreads();
        cur ^= 1;
    }

#pragma unroll
    for (int i = 0; i < 4; i++) {
#pragma unroll
        for (int j = 0; j < 4; j++) {
            const int col  = n0 + wn * 64 + j * 16 + ll;
            const int rowb = m0 + wm * 64 + i * 16 + quad * 4;
            f32x4 a = acc[i][j];
#pragma unroll
            for (int r = 0; r < 4; r++)
                out[(size_t)(rowb + r) * 512 + col] = a[r];
        }
    }
}

extern "C" void kernel_launch(void* const* d_in, const int* in_sizes, int n_in,
                              void* d_out, int out_size, void* d_ws, size_t ws_size,
                              hipStream_t stream) {
    (void)in_sizes; (void)n_in; (void)out_size; (void)ws_size;
    const float* x    = (const float*)d_in[0];
    const float* bias = (const float*)d_in[1];
    const float* Wq_w = (const float*)d_in[2];
    const float* Wq_b = (const float*)d_in[3];
    const float* Wk_w = (const float*)d_in[4];
    const float* Wk_b = (const float*)d_in[5];
    const float* Wv_w = (const float*)d_in[6];
    const float* Wv_b = (const float*)d_in[7];
    float* out = (float*)d_out;

    // workspace layout (bf16 elements)
    bf16_t* Xb = (bf16_t*)d_ws;                    // 16384 x 512
    bf16_t* Wb = Xb + (size_t)16384 * 512;         // 3 x 512 x 512
    bf16_t* Qb = Wb + (size_t)3 * 512 * 512;       // 16384 x 512 (pre-scaled 1/sqrt(D))
    bf16_t* Kb = Qb + (size_t)16384 * 512;         // 16384 x 512
    bf16_t* Vt = Kb + (size_t)16384 * 512;         // 4 x 512 x 4096 (transposed V)
    bf16_t* P  = Vt + (size_t)16384 * 512;         // 4 x 4096 x 4096
    // bf16 bias scratch: d_out (33,554,432 B) == 4096*4096*2 B exactly; out is
    // dead until pv_gemm overwrites it at the end.
    bf16_t* Bb = (bf16_t*)d_out;

    cvt_f32_bf16<<<8192, 256, 0, stream>>>(x, Xb, 2097152);
    cvt_w3<<<768, 256, 0, stream>>>(Wq_w, Wk_w, Wv_w, Wb);

    // projections (blocks 0..1535) + bias f32->bf16 tail (blocks 1536..3583)
    proj_all<<<3584, 256, 0, stream>>>(Xb, Wb, Wq_b, Wk_b, Wv_b, Qb, Kb, Vt,
                                       bias, Bb);
    // scores + sigmoid (2-phase dbuf, bf16 bias)
    scores_sig<<<4096, 256, 0, stream>>>(Qb, Kb, Bb, P);
    // out = P * V, 128x128 tiles, BK=64, 2-phase dbuf
    pv_gemm<<<dim3(4, 32, 4), 256, 0, stream>>>(P, Vt, out);
}

// Round 9
// 366.747 us; speedup vs baseline: 1.0930x; 1.0674x over previous
//
#include <hip/hip_runtime.h>
#include <hip/hip_bf16.h>
#include <stdint.h>

typedef unsigned short bf16_t;
typedef __attribute__((ext_vector_type(4))) short s4v;
typedef __attribute__((ext_vector_type(8))) short short8;
typedef __attribute__((ext_vector_type(4))) float f32x4;

__device__ __forceinline__ bf16_t f2b(float f) {
    union { float f; uint32_t u; } v; v.f = f;
    uint32_t u = v.u;
    return (bf16_t)((u + 0x7FFFu + ((u >> 16) & 1u)) >> 16);
}

// ---------- all input conversions in ONE launch ----------
// blocks 0..8191: x (2097152 float4s) ; blocks 8192..8959: 3 weight mats
__global__ __launch_bounds__(256) void cvt_all(const float* __restrict__ x,
                                               bf16_t* __restrict__ Xb,
                                               const float* __restrict__ a,
                                               const float* __restrict__ b,
                                               const float* __restrict__ c,
                                               bf16_t* __restrict__ Wb) {
    int i = blockIdx.x * 256 + threadIdx.x;
    if (i < 2097152) {
        float4 f = ((const float4*)x)[i];
        ushort4 o;
        o.x = f2b(f.x); o.y = f2b(f.y); o.z = f2b(f.z); o.w = f2b(f.w);
        ((ushort4*)Xb)[i] = o;
    } else {
        int j = i - 2097152;              // 0..196607
        const int which = j >> 16;
        const int idx   = j & 65535;
        const float* src = (which == 0) ? a : (which == 1) ? b : c;
        float4 f = ((const float4*)src)[idx];
        ushort4 o;
        o.x = f2b(f.x); o.y = f2b(f.y); o.z = f2b(f.z); o.w = f2b(f.w);
        ((ushort4*)Wb)[j] = o;
    }
}

__device__ __forceinline__ void lds_dma16(const void* g, void* l) {
    __builtin_amdgcn_global_load_lds(
        (const __attribute__((address_space(1))) void*)g,
        (__attribute__((address_space(3))) void*)l, 16, 0, 0);
}

// BK=64 swizzle contract: LDS[row][ch] holds global chunk (ch ^ (row&7));
// reader wanting global chunk g of row r reads LDS[r][g ^ (r&7)].
// 2-phase loop contract (T3 minimum recipe):
//   prologue: STAGE(buf0, kt=0); barrier.
//   iter kt:  STAGE(buf[cur^1], kt+1); ds_read+MFMA from buf[cur];
//             __syncthreads(); cur ^= 1.   One barrier per K-step.
// XCD decode assumption: consecutive blockIdx round-robin across 8 XCDs, so
// bid&7 is a stable XCD id; give each XCD a CONTIGUOUS chunk of the verified
// tile order with sharing-siblings adjacent (round-1 lesson: never stride the
// tile walk).

// ---------- projections: Q/K/V fused, flat grid (1536 blocks) ----------
__global__ __launch_bounds__(256)
void proj_all(const bf16_t* __restrict__ Xb, const bf16_t* __restrict__ Wb,
              const float* __restrict__ qb, const float* __restrict__ kb,
              const float* __restrict__ vb,
              bf16_t* __restrict__ Qb, bf16_t* __restrict__ Kb,
              bf16_t* __restrict__ Vt)
{
    __shared__ __align__(16) bf16_t lds[2][16384];   // 64 KB: 2 x (A 16KB | B 16KB)

    const int tid  = threadIdx.x;
    const int bid  = blockIdx.x;
    const int lane = tid & 63;
    const int w    = tid >> 6;
    const int wm   = w & 1, wn = w >> 1;
    const int ll   = lane & 15;
    const int quad = lane >> 4;

    // xcd x owns m-panels [16x..16x+15]; inner = 4n x 3z per panel.
    const int x     = bid & 7;
    const int g     = bid >> 3;        // 0..191
    const int mi    = x * 16 + g / 12; // 0..127
    const int inner = g % 12;
    const int m0 = mi * 128;
    const int n0 = (inner & 3) * 128;
    const int z  = inner >> 2;         // 0..2

    const bf16_t* A = Xb;
    const bf16_t* B = Wb + z * 262144;

    auto stage = [&](int kt, int b) {
#pragma unroll
        for (int c = 0; c < 4; ++c) {
            const int base = (c * 4 + w) * 64;
            const int slot = base + lane;
            const int row  = slot >> 3;
            const int kc   = ((slot & 7) ^ (row & 7)) << 3;
            lds_dma16(A + (size_t)(m0 + row) * 512 + kt * 64 + kc, (char*)&lds[b][0]    + base * 16);
            lds_dma16(B + (size_t)(n0 + row) * 512 + kt * 64 + kc, (char*)&lds[b][8192] + base * 16);
        }
    };

    f32x4 acc[4][4];
#pragma unroll
    for (int i = 0; i < 4; i++)
#pragma unroll
        for (int j = 0; j < 4; j++) acc[i][j] = (f32x4){0.f, 0.f, 0.f, 0.f};

    stage(0, 0);
    __syncthreads();
    int cur = 0;
    for (int kt = 0; kt < 8; ++kt) {
        if (kt < 7) stage(kt + 1, cur ^ 1);
        const bf16_t* lsA = &lds[cur][0];
        const bf16_t* lsB = &lds[cur][8192];
#pragma unroll
        for (int t = 0; t < 2; t++) {
            short8 af[4], bf[4];
#pragma unroll
            for (int i = 0; i < 4; i++) {
                const int ri = wm * 64 + i * 16 + ll;
                const int rj = wn * 64 + i * 16 + ll;
                af[i] = *(const short8*)(lsA + ri * 64 + (((t * 4 + quad) ^ (ll & 7)) << 3));
                bf[i] = *(const short8*)(lsB + rj * 64 + (((t * 4 + quad) ^ (ll & 7)) << 3));
            }
#pragma unroll
            for (int i = 0; i < 4; i++)
#pragma unroll
                for (int j = 0; j < 4; j++)
                    acc[i][j] = __builtin_amdgcn_mfma_f32_16x16x32_bf16(af[i], bf[j], acc[i][j], 0, 0, 0);
        }
        __syncthreads();
        cur ^= 1;
    }

    // ---- epilogue: bounce through LDS for coalesced 16B stores ----
    bf16_t* wbuf = &lds[0][0] + w * 4096;     // 64x64 bf16 per wave (32 KB in buf0)
    const float inv = 0.044194173824159216f;  // 1/sqrt(512)

    if (z != 2) {
        const float* bptr = (z == 0) ? qb : kb;
        const float scl   = (z == 0) ? inv : 1.0f;
#pragma unroll
        for (int j = 0; j < 4; j++) {
            const int colL = j * 16 + ll;
            const float bv = bptr[n0 + wn * 64 + colL];
#pragma unroll
            for (int i = 0; i < 4; i++) {
                f32x4 a = acc[i][j];
#pragma unroll
                for (int r = 0; r < 4; r++) {
                    const int rowL = i * 16 + quad * 4 + r;
                    wbuf[rowL * 64 + (colL ^ ((rowL & 7) << 3))] = f2b((a[r] + bv) * scl);
                }
            }
        }
        __syncthreads();
        bf16_t* dst = (z == 0) ? Qb : Kb;
        const int rowg0 = m0 + wm * 64;
        const int colg0 = n0 + wn * 64;
#pragma unroll
        for (int k = 0; k < 8; k++) {
            const int rowL = (lane >> 3) + k * 8;
            const int c0   = (lane & 7) * 8;
            short8 vv = *(const short8*)(wbuf + rowL * 64 + (c0 ^ ((rowL & 7) << 3)));
            *(short8*)(dst + (size_t)(rowg0 + rowL) * 512 + colg0 + c0) = vv;
        }
    } else {
        // V: store transposed Vt[b][d][s]; bounce col-major (d-major)
#pragma unroll
        for (int j = 0; j < 4; j++) {
            const int d = j * 16 + ll;
            const float bv = vb[n0 + wn * 64 + d];
#pragma unroll
            for (int i = 0; i < 4; i++) {
                f32x4 a = acc[i][j];
                s4v pk;
                pk[0] = (short)f2b(a[0] + bv);
                pk[1] = (short)f2b(a[1] + bv);
                pk[2] = (short)f2b(a[2] + bv);
                pk[3] = (short)f2b(a[3] + bv);
                const int sB = i * 16 + quad * 4;
                *(s4v*)(wbuf + d * 64 + (sB ^ ((d & 7) << 3))) = pk;
            }
        }
        __syncthreads();
        const int rowg0 = m0 + wm * 64;
        const int b  = rowg0 >> 12;
        const int s0 = rowg0 & 4095;
        const int d0 = n0 + wn * 64;
#pragma unroll
        for (int k = 0; k < 8; k++) {
            const int dL = (lane >> 3) + k * 8;
            const int c0 = (lane & 7) * 8;
            short8 vv = *(const short8*)(wbuf + dL * 64 + (c0 ^ ((dL & 7) << 3)));
            *(short8*)(Vt + ((size_t)b * 512 + d0 + dL) * 4096 + s0 + c0) = vv;
        }
    }
}

// ---------- scores: P = sigmoid(Q K^T + bias), 2-phase dbuf, XCD-chunked ----------
// x = bid&7 (XCD); per XCD: contiguous 128-tile chunk of the supertile order,
// z innermost -> 4 batch-siblings (same 64KB fp32 bias tile) run back-to-back
// on the SAME XCD => bias L2-resident across z=1..3.
__global__ __launch_bounds__(256)
void scores_sig(const bf16_t* __restrict__ Qb, const bf16_t* __restrict__ Kb,
                const float* __restrict__ bias, bf16_t* __restrict__ P)
{
    __shared__ __align__(16) bf16_t lds[2][16384];   // 64 KB

    const int tid  = threadIdx.x;
    const int lane = tid & 63;
    const int w    = tid >> 6;
    const int wm   = w & 1, wn = w >> 1;
    const int ll   = lane & 15;
    const int quad = lane >> 4;

    const int bx  = blockIdx.x;           // 0..4095
    const int x   = bx & 7;               // XCD
    const int s   = bx >> 3;              // 0..511
    const int z   = s & 3;                // z innermost per XCD
    const int t_  = x * 128 + (s >> 2);   // contiguous chunk, 0..1023
    const int sup = t_ >> 5;              // supertile (8m x 4n)
    const int win = t_ & 31;              // 4m x 8n within
    const int m0  = ((sup >> 2) * 4 + (win & 3)) * 128;
    const int n0  = ((sup & 3) * 8 + (win >> 2)) * 128;

    const bf16_t* A = Qb + (size_t)z * 2097152;
    const bf16_t* B = Kb + (size_t)z * 2097152;
    bf16_t* out = P + (size_t)z * 16777216;

    auto stage = [&](int kt, int b) {
#pragma unroll
        for (int c = 0; c < 4; ++c) {
            const int base = (c * 4 + w) * 64;
            const int slot = base + lane;
            const int row  = slot >> 3;
            const int kc   = ((slot & 7) ^ (row & 7)) << 3;
            lds_dma16(A + (size_t)(m0 + row) * 512 + kt * 64 + kc, (char*)&lds[b][0]    + base * 16);
            lds_dma16(B + (size_t)(n0 + row) * 512 + kt * 64 + kc, (char*)&lds[b][8192] + base * 16);
        }
    };

    f32x4 acc[4][4];
#pragma unroll
    for (int i = 0; i < 4; i++)
#pragma unroll
        for (int j = 0; j < 4; j++) acc[i][j] = (f32x4){0.f, 0.f, 0.f, 0.f};

    stage(0, 0);
    __syncthreads();
    int cur = 0;
    for (int kt = 0; kt < 8; ++kt) {
        if (kt < 7) stage(kt + 1, cur ^ 1);
        const bf16_t* lsA = &lds[cur][0];
        const bf16_t* lsB = &lds[cur][8192];
#pragma unroll
        for (int t = 0; t < 2; t++) {
            short8 af[4], bf[4];
#pragma unroll
            for (int i = 0; i < 4; i++) {
                const int ri = wm * 64 + i * 16 + ll;
                const int rj = wn * 64 + i * 16 + ll;
                af[i] = *(const short8*)(lsA + ri * 64 + (((t * 4 + quad) ^ (ll & 7)) << 3));
                bf[i] = *(const short8*)(lsB + rj * 64 + (((t * 4 + quad) ^ (ll & 7)) << 3));
            }
#pragma unroll
            for (int i = 0; i < 4; i++)
#pragma unroll
                for (int j = 0; j < 4; j++)
                    acc[i][j] = __builtin_amdgcn_mfma_f32_16x16x32_bf16(af[i], bf[j], acc[i][j], 0, 0, 0);
        }
        __syncthreads();
        cur ^= 1;
    }

    // sigmoid epilogue: fp32 bias (L2-hit for z=1..3 on this XCD), truncated pack
#pragma unroll
    for (int i = 0; i < 4; i++) {
#pragma unroll
        for (int j = 0; j < 4; j++) {
            const int col  = n0 + wn * 64 + j * 16 + ll;
            const int rowb = m0 + wm * 64 + i * 16 + quad * 4;
            f32x4 a = acc[i][j];
#pragma unroll
            for (int r = 0; r < 4; r++) {
                const int row = rowb + r;
                const float v = a[r] + bias[(size_t)row * 4096 + col];
                const float p = __builtin_amdgcn_rcpf(1.f + __expf(-v));
                out[(size_t)row * 4096 + col] = (bf16_t)(__float_as_uint(p) >> 16);
            }
        }
    }
}

// ---------- PV: out = P * Vt^T, 128x128, BK=64, 2-phase dbuf, XCD-chunked ----------
// x = bid&7 (XCD); per XCD 16 (m,z)-strips x 4 n-tiles, n innermost -> the 4
// n-siblings sharing a P m-strip run lockstep on ONE XCD, reading identical
// A-chunks each k-step => P HBM traffic ~134 MB instead of ~536.
__global__ __launch_bounds__(256)
void pv_gemm(const bf16_t* __restrict__ P, const bf16_t* __restrict__ Vt,
             float* __restrict__ outg)
{
    __shared__ __align__(16) bf16_t lds[2][16384];   // 64 KB

    const int tid  = threadIdx.x;
    const int lane = tid & 63;
    const int w    = tid >> 6;
    const int wm   = w & 1, wn = w >> 1;
    const int ll   = lane & 15;
    const int quad = lane >> 4;

    const int bid   = blockIdx.x;        // 0..511
    const int x     = bid & 7;
    const int g     = bid >> 3;          // 0..63
    const int strip = x * 16 + (g >> 2); // 0..127
    const int n0    = (g & 3) * 128;
    const int m0    = (strip & 31) * 128;
    const int z     = strip >> 5;

    const bf16_t* A = P + (size_t)z * 16777216;   // [4096][4096]
    const bf16_t* B = Vt + (size_t)z * 2097152;   // [512][4096]
    float* out = outg + (size_t)z * 2097152;

    auto stage = [&](int kt, int b) {
#pragma unroll
        for (int c = 0; c < 4; ++c) {
            const int base = (c * 4 + w) * 64;
            const int slot = base + lane;
            const int row  = slot >> 3;
            const int kc   = ((slot & 7) ^ (row & 7)) << 3;
            lds_dma16(A + (size_t)(m0 + row) * 4096 + kt * 64 + kc, (char*)&lds[b][0]    + base * 16);
            lds_dma16(B + (size_t)(n0 + row) * 4096 + kt * 64 + kc, (char*)&lds[b][8192] + base * 16);
        }
    };

    f32x4 acc[4][4];
#pragma unroll
    for (int i = 0; i < 4; i++)
#pragma unroll
        for (int j = 0; j < 4; j++) acc[i][j] = (f32x4){0.f, 0.f, 0.f, 0.f};

    stage(0, 0);
    __syncthreads();
    int cur = 0;
    for (int kt = 0; kt < 64; ++kt) {
        if (kt < 63) stage(kt + 1, cur ^ 1);
        const bf16_t* lsA = &lds[cur][0];
        const bf16_t* lsB = &lds[cur][8192];
#pragma unroll
        for (int t = 0; t < 2; t++) {
            short8 af[4], bf[4];
#pragma unroll
            for (int i = 0; i < 4; i++) {
                const int ri = wm * 64 + i * 16 + ll;
                const int rj = wn * 64 + i * 16 + ll;
                af[i] = *(const short8*)(lsA + ri * 64 + (((t * 4 + quad) ^ (ll & 7)) << 3));
                bf[i] = *(const short8*)(lsB + rj * 64 + (((t * 4 + quad) ^ (ll & 7)) << 3));
            }
#pragma unroll
            for (int i = 0; i < 4; i++)
#pragma unroll
                for (int j = 0; j < 4; j++)
                    acc[i][j] = __builtin_amdgcn_mfma_f32_16x16x32_bf16(af[i], bf[j], acc[i][j], 0, 0, 0);
        }
        __syncthreads();
        cur ^= 1;
    }

#pragma unroll
    for (int i = 0; i < 4; i++) {
#pragma unroll
        for (int j = 0; j < 4; j++) {
            const int col  = n0 + wn * 64 + j * 16 + ll;
            const int rowb = m0 + wm * 64 + i * 16 + quad * 4;
            f32x4 a = acc[i][j];
#pragma unroll
            for (int r = 0; r < 4; r++)
                out[(size_t)(rowb + r) * 512 + col] = a[r];
        }
    }
}

extern "C" void kernel_launch(void* const* d_in, const int* in_sizes, int n_in,
                              void* d_out, int out_size, void* d_ws, size_t ws_size,
                              hipStream_t stream) {
    (void)in_sizes; (void)n_in; (void)out_size; (void)ws_size;
    const float* x    = (const float*)d_in[0];
    const float* bias = (const float*)d_in[1];
    const float* Wq_w = (const float*)d_in[2];
    const float* Wq_b = (const float*)d_in[3];
    const float* Wk_w = (const float*)d_in[4];
    const float* Wk_b = (const float*)d_in[5];
    const float* Wv_w = (const float*)d_in[6];
    const float* Wv_b = (const float*)d_in[7];
    float* out = (float*)d_out;

    // workspace layout (bf16 elements)
    bf16_t* Xb = (bf16_t*)d_ws;                    // 16384 x 512
    bf16_t* Wb = Xb + (size_t)16384 * 512;         // 3 x 512 x 512
    bf16_t* Qb = Wb + (size_t)3 * 512 * 512;       // 16384 x 512 (pre-scaled 1/sqrt(D))
    bf16_t* Kb = Qb + (size_t)16384 * 512;         // 16384 x 512
    bf16_t* Vt = Kb + (size_t)16384 * 512;         // 4 x 512 x 4096 (transposed V)
    bf16_t* P  = Vt + (size_t)16384 * 512;         // 4 x 4096 x 4096

    // all input conversions in one launch (x + 3 weight matrices)
    cvt_all<<<8960, 256, 0, stream>>>(x, Xb, Wq_w, Wk_w, Wv_w, Wb);

    // projections (XCD-chunked m-panels)
    proj_all<<<1536, 256, 0, stream>>>(Xb, Wb, Wq_b, Wk_b, Wv_b, Qb, Kb, Vt);
    // scores + sigmoid (2-phase dbuf, fp32 bias, XCD-chunked w/ z innermost)
    scores_sig<<<4096, 256, 0, stream>>>(Qb, Kb, bias, P);
    // out = P * V (2-phase dbuf, XCD-chunked w/ n innermost per P-strip)
    pv_gemm<<<512, 256, 0, stream>>>(P, Vt, out);
}

// Round 10
// 359.444 us; speedup vs baseline: 1.1152x; 1.0203x over previous
//
#include <hip/hip_runtime.h>
#include <hip/hip_bf16.h>
#include <stdint.h>

typedef unsigned short bf16_t;
typedef __attribute__((ext_vector_type(4))) short s4v;
typedef __attribute__((ext_vector_type(8))) short short8;
typedef __attribute__((ext_vector_type(4))) float f32x4;

__device__ __forceinline__ bf16_t f2b(float f) {
    union { float f; uint32_t u; } v; v.f = f;
    uint32_t u = v.u;
    return (bf16_t)((u + 0x7FFFu + ((u >> 16) & 1u)) >> 16);
}

__device__ __forceinline__ float b2f(bf16_t b) {
    union { uint32_t u; float f; } v;
    v.u = ((uint32_t)b) << 16;
    return v.f;
}

// ---------- all input conversions in ONE launch ----------
// blocks 0..8191: x (2097152 float4s) ; blocks 8192..8959: 3 weight mats
__global__ __launch_bounds__(256) void cvt_all(const float* __restrict__ x,
                                               bf16_t* __restrict__ Xb,
                                               const float* __restrict__ a,
                                               const float* __restrict__ b,
                                               const float* __restrict__ c,
                                               bf16_t* __restrict__ Wb) {
    int i = blockIdx.x * 256 + threadIdx.x;
    if (i < 2097152) {
        float4 f = ((const float4*)x)[i];
        ushort4 o;
        o.x = f2b(f.x); o.y = f2b(f.y); o.z = f2b(f.z); o.w = f2b(f.w);
        ((ushort4*)Xb)[i] = o;
    } else {
        int j = i - 2097152;              // 0..196607
        const int which = j >> 16;
        const int idx   = j & 65535;
        const float* src = (which == 0) ? a : (which == 1) ? b : c;
        float4 f = ((const float4*)src)[idx];
        ushort4 o;
        o.x = f2b(f.x); o.y = f2b(f.y); o.z = f2b(f.z); o.w = f2b(f.w);
        ((ushort4*)Wb)[j] = o;
    }
}

__device__ __forceinline__ void lds_dma16(const void* g, void* l) {
    __builtin_amdgcn_global_load_lds(
        (const __attribute__((address_space(1))) void*)g,
        (__attribute__((address_space(3))) void*)l, 16, 0, 0);
}

// BK=64 swizzle contract: LDS[row][ch] holds global chunk (ch ^ (row&7));
// reader wanting global chunk g of row r reads LDS[r][g ^ (r&7)].
// 2-phase loop contract (T3 minimum recipe):
//   prologue: STAGE(buf0, kt=0); barrier.
//   iter kt:  STAGE(buf[cur^1], kt+1); ds_read+MFMA from buf[cur];
//             __syncthreads(); cur ^= 1.   One barrier per K-step.

// ---------- projections: Q/K/V fused (1536 blocks) + bias f32->bf16 streamed
// into the k-loop's idle memory slots (r8 lesson: tail blocks serialize; the
// conversion must ride INSIDE the latency-bound loop to overlap) ----------
__global__ __launch_bounds__(256)
void proj_all(const bf16_t* __restrict__ Xb, const bf16_t* __restrict__ Wb,
              const float* __restrict__ qb, const float* __restrict__ kb,
              const float* __restrict__ vb,
              bf16_t* __restrict__ Qb, bf16_t* __restrict__ Kb,
              bf16_t* __restrict__ Vt,
              const float* __restrict__ biasf, bf16_t* __restrict__ biasb)
{
    __shared__ __align__(16) bf16_t lds[2][16384];   // 64 KB: 2 x (A 16KB | B 16KB)

    const int tid  = threadIdx.x;
    const int bid  = blockIdx.x;
    const int lane = tid & 63;
    const int w    = tid >> 6;
    const int wm   = w & 1, wn = w >> 1;
    const int ll   = lane & 15;
    const int quad = lane >> 4;

    // xcd x owns m-panels [16x..16x+15]; inner = 4n x 3z per panel.
    const int x     = bid & 7;
    const int g     = bid >> 3;        // 0..191
    const int mi    = x * 16 + g / 12; // 0..127
    const int inner = g % 12;
    const int m0 = mi * 128;
    const int n0 = (inner & 3) * 128;
    const int z  = inner >> 2;         // 0..2

    const bf16_t* A = Xb;
    const bf16_t* B = Wb + z * 262144;

    auto stage = [&](int kt, int b) {
#pragma unroll
        for (int c = 0; c < 4; ++c) {
            const int base = (c * 4 + w) * 64;
            const int slot = base + lane;
            const int row  = slot >> 3;
            const int kc   = ((slot & 7) ^ (row & 7)) << 3;
            lds_dma16(A + (size_t)(m0 + row) * 512 + kt * 64 + kc, (char*)&lds[b][0]    + base * 16);
            lds_dma16(B + (size_t)(n0 + row) * 512 + kt * 64 + kc, (char*)&lds[b][8192] + base * 16);
        }
    };

    f32x4 acc[4][4];
#pragma unroll
    for (int i = 0; i < 4; i++)
#pragma unroll
        for (int j = 0; j < 4; j++) acc[i][j] = (f32x4){0.f, 0.f, 0.f, 0.f};

    stage(0, 0);
    __syncthreads();
    int cur = 0;
    for (int kt = 0; kt < 8; ++kt) {
        if (kt < 7) stage(kt + 1, cur ^ 1);

        // ---- bias f32->bf16 chunk: independent mem ops, hidden under MFMA.
        // (bid,kt,tid) covers [0,3145728) once; +offset covers [3145728,4194304).
        {
            const int idx = (bid * 8 + kt) * 256 + tid;     // < 3145728
            float4 f = ((const float4*)biasf)[idx];
            ushort4 o;
            o.x = f2b(f.x); o.y = f2b(f.y); o.z = f2b(f.z); o.w = f2b(f.w);
            ((ushort4*)biasb)[idx] = o;
            const int idx2 = idx + 3145728;
            if (idx2 < 4194304) {
                float4 f2 = ((const float4*)biasf)[idx2];
                ushort4 o2;
                o2.x = f2b(f2.x); o2.y = f2b(f2.y); o2.z = f2b(f2.z); o2.w = f2b(f2.w);
                ((ushort4*)biasb)[idx2] = o2;
            }
        }

        const bf16_t* lsA = &lds[cur][0];
        const bf16_t* lsB = &lds[cur][8192];
#pragma unroll
        for (int t = 0; t < 2; t++) {
            short8 af[4], bf[4];
#pragma unroll
            for (int i = 0; i < 4; i++) {
                const int ri = wm * 64 + i * 16 + ll;
                const int rj = wn * 64 + i * 16 + ll;
                af[i] = *(const short8*)(lsA + ri * 64 + (((t * 4 + quad) ^ (ll & 7)) << 3));
                bf[i] = *(const short8*)(lsB + rj * 64 + (((t * 4 + quad) ^ (ll & 7)) << 3));
            }
#pragma unroll
            for (int i = 0; i < 4; i++)
#pragma unroll
                for (int j = 0; j < 4; j++)
                    acc[i][j] = __builtin_amdgcn_mfma_f32_16x16x32_bf16(af[i], bf[j], acc[i][j], 0, 0, 0);
        }
        __syncthreads();
        cur ^= 1;
    }

    // ---- epilogue: bounce through LDS for coalesced 16B stores ----
    bf16_t* wbuf = &lds[0][0] + w * 4096;     // 64x64 bf16 per wave (32 KB in buf0)
    const float inv = 0.044194173824159216f;  // 1/sqrt(512)

    if (z != 2) {
        const float* bptr = (z == 0) ? qb : kb;
        const float scl   = (z == 0) ? inv : 1.0f;
#pragma unroll
        for (int j = 0; j < 4; j++) {
            const int colL = j * 16 + ll;
            const float bv = bptr[n0 + wn * 64 + colL];
#pragma unroll
            for (int i = 0; i < 4; i++) {
                f32x4 a = acc[i][j];
#pragma unroll
                for (int r = 0; r < 4; r++) {
                    const int rowL = i * 16 + quad * 4 + r;
                    wbuf[rowL * 64 + (colL ^ ((rowL & 7) << 3))] = f2b((a[r] + bv) * scl);
                }
            }
        }
        __syncthreads();
        bf16_t* dst = (z == 0) ? Qb : Kb;
        const int rowg0 = m0 + wm * 64;
        const int colg0 = n0 + wn * 64;
#pragma unroll
        for (int k = 0; k < 8; k++) {
            const int rowL = (lane >> 3) + k * 8;
            const int c0   = (lane & 7) * 8;
            short8 vv = *(const short8*)(wbuf + rowL * 64 + (c0 ^ ((rowL & 7) << 3)));
            *(short8*)(dst + (size_t)(rowg0 + rowL) * 512 + colg0 + c0) = vv;
        }
    } else {
        // V: store transposed Vt[b][d][s]; bounce col-major (d-major)
#pragma unroll
        for (int j = 0; j < 4; j++) {
            const int d = j * 16 + ll;
            const float bv = vb[n0 + wn * 64 + d];
#pragma unroll
            for (int i = 0; i < 4; i++) {
                f32x4 a = acc[i][j];
                s4v pk;
                pk[0] = (short)f2b(a[0] + bv);
                pk[1] = (short)f2b(a[1] + bv);
                pk[2] = (short)f2b(a[2] + bv);
                pk[3] = (short)f2b(a[3] + bv);
                const int sB = i * 16 + quad * 4;
                *(s4v*)(wbuf + d * 64 + (sB ^ ((d & 7) << 3))) = pk;
            }
        }
        __syncthreads();
        const int rowg0 = m0 + wm * 64;
        const int b  = rowg0 >> 12;
        const int s0 = rowg0 & 4095;
        const int d0 = n0 + wn * 64;
#pragma unroll
        for (int k = 0; k < 8; k++) {
            const int dL = (lane >> 3) + k * 8;
            const int c0 = (lane & 7) * 8;
            short8 vv = *(const short8*)(wbuf + dL * 64 + (c0 ^ ((dL & 7) << 3)));
            *(short8*)(Vt + ((size_t)b * 512 + d0 + dL) * 4096 + s0 + c0) = vv;
        }
    }
}

// ---------- scores: P = sigmoid(Q K^T + bias_bf16), 2-phase dbuf ----------
// r7-MEASURED config (114 us): z-fastest grid (3.0 TB/s effective) + bf16 bias
// epilogue (344 MB total traffic).
__global__ __launch_bounds__(256)
void scores_sig(const bf16_t* __restrict__ Qb, const bf16_t* __restrict__ Kb,
                const bf16_t* __restrict__ biasb, bf16_t* __restrict__ P)
{
    __shared__ __align__(16) bf16_t lds[2][16384];   // 64 KB

    const int tid  = threadIdx.x;
    const int lane = tid & 63;
    const int w    = tid >> 6;
    const int wm   = w & 1, wn = w >> 1;
    const int ll   = lane & 15;
    const int quad = lane >> 4;

    const int bx  = blockIdx.x;
    const int z   = bx & 3;
    const int t_  = bx >> 2;              // 0..1023
    const int sup = t_ >> 5;              // 32 supertiles (8 in m x 4 in n)
    const int win = t_ & 31;              // 32 tiles per supertile (4m x 8n)
    const int m0  = ((sup >> 2) * 4 + (win & 3)) * 128;
    const int n0  = ((sup & 3) * 8 + (win >> 2)) * 128;

    const bf16_t* A = Qb + (size_t)z * 2097152;
    const bf16_t* B = Kb + (size_t)z * 2097152;
    bf16_t* out = P + (size_t)z * 16777216;

    auto stage = [&](int kt, int b) {
#pragma unroll
        for (int c = 0; c < 4; ++c) {
            const int base = (c * 4 + w) * 64;
            const int slot = base + lane;
            const int row  = slot >> 3;
            const int kc   = ((slot & 7) ^ (row & 7)) << 3;
            lds_dma16(A + (size_t)(m0 + row) * 512 + kt * 64 + kc, (char*)&lds[b][0]    + base * 16);
            lds_dma16(B + (size_t)(n0 + row) * 512 + kt * 64 + kc, (char*)&lds[b][8192] + base * 16);
        }
    };

    f32x4 acc[4][4];
#pragma unroll
    for (int i = 0; i < 4; i++)
#pragma unroll
        for (int j = 0; j < 4; j++) acc[i][j] = (f32x4){0.f, 0.f, 0.f, 0.f};

    stage(0, 0);
    __syncthreads();
    int cur = 0;
    for (int kt = 0; kt < 8; ++kt) {
        if (kt < 7) stage(kt + 1, cur ^ 1);
        const bf16_t* lsA = &lds[cur][0];
        const bf16_t* lsB = &lds[cur][8192];
#pragma unroll
        for (int t = 0; t < 2; t++) {
            short8 af[4], bf[4];
#pragma unroll
            for (int i = 0; i < 4; i++) {
                const int ri = wm * 64 + i * 16 + ll;
                const int rj = wn * 64 + i * 16 + ll;
                af[i] = *(const short8*)(lsA + ri * 64 + (((t * 4 + quad) ^ (ll & 7)) << 3));
                bf[i] = *(const short8*)(lsB + rj * 64 + (((t * 4 + quad) ^ (ll & 7)) << 3));
            }
#pragma unroll
            for (int i = 0; i < 4; i++)
#pragma unroll
                for (int j = 0; j < 4; j++)
                    acc[i][j] = __builtin_amdgcn_mfma_f32_16x16x32_bf16(af[i], bf[j], acc[i][j], 0, 0, 0);
        }
        __syncthreads();
        cur ^= 1;
    }

    // sigmoid epilogue: bf16 bias (shared by 4 batch-siblings), truncated pack
#pragma unroll
    for (int i = 0; i < 4; i++) {
#pragma unroll
        for (int j = 0; j < 4; j++) {
            const int col  = n0 + wn * 64 + j * 16 + ll;
            const int rowb = m0 + wm * 64 + i * 16 + quad * 4;
            f32x4 a = acc[i][j];
#pragma unroll
            for (int r = 0; r < 4; r++) {
                const int row = rowb + r;
                const float v = a[r] + b2f(biasb[(size_t)row * 4096 + col]);
                const float p = __builtin_amdgcn_rcpf(1.f + __expf(-v));
                out[(size_t)row * 4096 + col] = (bf16_t)(__float_as_uint(p) >> 16);
            }
        }
    }
}

// ---------- PV: out = P * Vt^T, 128x128, BK=64, 2-phase dbuf, XCD-chunked ----------
// x = bid&7 (XCD); per XCD 16 (m,z)-strips x 4 n-tiles, n innermost -> the 4
// n-siblings sharing a P m-strip run lockstep on ONE XCD (r9-verified win).
__global__ __launch_bounds__(256)
void pv_gemm(const bf16_t* __restrict__ P, const bf16_t* __restrict__ Vt,
             float* __restrict__ outg)
{
    __shared__ __align__(16) bf16_t lds[2][16384];   // 64 KB

    const int tid  = threadIdx.x;
    const int lane = tid & 63;
    const int w    = tid >> 6;
    const int wm   = w & 1, wn = w >> 1;
    const int ll   = lane & 15;
    const int quad = lane >> 4;

    const int bid   = blockIdx.x;        // 0..511
    const int x     = bid & 7;
    const int g     = bid >> 3;          // 0..63
    const int strip = x * 16 + (g >> 2); // 0..127
    const int n0    = (g & 3) * 128;
    const int m0    = (strip & 31) * 128;
    const int z     = strip >> 5;

    const bf16_t* A = P + (size_t)z * 16777216;   // [4096][4096]
    const bf16_t* B = Vt + (size_t)z * 2097152;   // [512][4096]
    float* out = outg + (size_t)z * 2097152;

    auto stage = [&](int kt, int b) {
#pragma unroll
        for (int c = 0; c < 4; ++c) {
            const int base = (c * 4 + w) * 64;
            const int slot = base + lane;
            const int row  = slot >> 3;
            const int kc   = ((slot & 7) ^ (row & 7)) << 3;
            lds_dma16(A + (size_t)(m0 + row) * 4096 + kt * 64 + kc, (char*)&lds[b][0]    + base * 16);
            lds_dma16(B + (size_t)(n0 + row) * 4096 + kt * 64 + kc, (char*)&lds[b][8192] + base * 16);
        }
    };

    f32x4 acc[4][4];
#pragma unroll
    for (int i = 0; i < 4; i++)
#pragma unroll
        for (int j = 0; j < 4; j++) acc[i][j] = (f32x4){0.f, 0.f, 0.f, 0.f};

    stage(0, 0);
    __syncthreads();
    int cur = 0;
    for (int kt = 0; kt < 64; ++kt) {
        if (kt < 63) stage(kt + 1, cur ^ 1);
        const bf16_t* lsA = &lds[cur][0];
        const bf16_t* lsB = &lds[cur][8192];
#pragma unroll
        for (int t = 0; t < 2; t++) {
            short8 af[4], bf[4];
#pragma unroll
            for (int i = 0; i < 4; i++) {
                const int ri = wm * 64 + i * 16 + ll;
                const int rj = wn * 64 + i * 16 + ll;
                af[i] = *(const short8*)(lsA + ri * 64 + (((t * 4 + quad) ^ (ll & 7)) << 3));
                bf[i] = *(const short8*)(lsB + rj * 64 + (((t * 4 + quad) ^ (ll & 7)) << 3));
            }
#pragma unroll
            for (int i = 0; i < 4; i++)
#pragma unroll
                for (int j = 0; j < 4; j++)
                    acc[i][j] = __builtin_amdgcn_mfma_f32_16x16x32_bf16(af[i], bf[j], acc[i][j], 0, 0, 0);
        }
        __syncthreads();
        cur ^= 1;
    }

#pragma unroll
    for (int i = 0; i < 4; i++) {
#pragma unroll
        for (int j = 0; j < 4; j++) {
            const int col  = n0 + wn * 64 + j * 16 + ll;
            const int rowb = m0 + wm * 64 + i * 16 + quad * 4;
            f32x4 a = acc[i][j];
#pragma unroll
            for (int r = 0; r < 4; r++)
                out[(size_t)(rowb + r) * 512 + col] = a[r];
        }
    }
}

extern "C" void kernel_launch(void* const* d_in, const int* in_sizes, int n_in,
                              void* d_out, int out_size, void* d_ws, size_t ws_size,
                              hipStream_t stream) {
    (void)in_sizes; (void)n_in; (void)out_size; (void)ws_size;
    const float* x    = (const float*)d_in[0];
    const float* bias = (const float*)d_in[1];
    const float* Wq_w = (const float*)d_in[2];
    const float* Wq_b = (const float*)d_in[3];
    const float* Wk_w = (const float*)d_in[4];
    const float* Wk_b = (const float*)d_in[5];
    const float* Wv_w = (const float*)d_in[6];
    const float* Wv_b = (const float*)d_in[7];
    float* out = (float*)d_out;

    // workspace layout (bf16 elements)
    bf16_t* Xb = (bf16_t*)d_ws;                    // 16384 x 512
    bf16_t* Wb = Xb + (size_t)16384 * 512;         // 3 x 512 x 512
    bf16_t* Qb = Wb + (size_t)3 * 512 * 512;       // 16384 x 512 (pre-scaled 1/sqrt(D))
    bf16_t* Kb = Qb + (size_t)16384 * 512;         // 16384 x 512
    bf16_t* Vt = Kb + (size_t)16384 * 512;         // 4 x 512 x 4096 (transposed V)
    bf16_t* P  = Vt + (size_t)16384 * 512;         // 4 x 4096 x 4096
    // bf16 bias scratch: d_out (33,554,432 B) == 4096*4096*2 B exactly; out is
    // dead until pv_gemm overwrites it at the end (r7/r8-verified aliasing).
    bf16_t* Bb = (bf16_t*)d_out;

    // all input conversions in one launch (x + 3 weight matrices)
    cvt_all<<<8960, 256, 0, stream>>>(x, Xb, Wq_w, Wk_w, Wv_w, Wb);

    // projections + bias cvt streamed into the k-loop (overlap)
    proj_all<<<1536, 256, 0, stream>>>(Xb, Wb, Wq_b, Wk_b, Wv_b, Qb, Kb, Vt,
                                       bias, Bb);
    // scores + sigmoid (r7-measured config: z-fastest grid, bf16 bias)
    scores_sig<<<4096, 256, 0, stream>>>(Qb, Kb, Bb, P);
    // out = P * V (2-phase dbuf, XCD-chunked w/ n innermost per P-strip)
    pv_gemm<<<512, 256, 0, stream>>>(P, Vt, out);
}